// Round 16
// baseline (540.813 us; speedup 1.0000x reference)
//
#include <hip/hip_runtime.h>
#include <hip/hip_bf16.h>

// E3nnSimpleEdgeBlock, two-stage factorized MFMA (R13 datapath, green @79.7us)
// + ONE change: __launch_bounds__(256, 8) forces VGPR <= 64, crossing the
// measured occupancy cliff (waves/SIMD halves at VGPR=64): residency cap goes
// 16 -> 32 waves/CU (LDS 18.9KB allows exactly 8 blocks/CU).
//
// Stage 1 (MFMA, static A): G_p,c[e,w] = sum_u a_c[e,u] * (scale*Wp)[u,v,w]
// Stage 2 (f32 VALU on D-frags): acc[e,w] += b_c[e,v] * G_p,c[e,w]
//
// mfma_f32_16x16x32_bf16 lane mapping (m89-verified):
//   A[row=l&15][k=8*(l>>4)+j]  B[k=8*(l>>4)+j][col=l&15]  D[row=4*(l>>4)+r][col=l&15]

typedef __attribute__((ext_vector_type(8))) short short8;   // 8 bf16 (4 VGPRs)
typedef __attribute__((ext_vector_type(4))) float f32x4;

static constexpr float C_OUT0    = 0.022097086912079608f; // 1/sqrt(2048)
static constexpr float C_OUT1    = 0.03125f;              // 1/sqrt(1024)
static constexpr float INV_SQRT3 = 0.57735026918962576f;
static constexpr float INV_SQRT6 = 0.40824829046386302f;

static __device__ __forceinline__ short bfbits(float x) {
    __hip_bfloat16 h = __float2bfloat16(x);
    return __builtin_bit_cast(short, h);
}

// ---------------------------------------------------------------------------
// prep (unchanged, post-timing-proven x9): bf16 B-fragment stream in d_ws.
// Layout: for v, frag f (0..9), lane l: 8 bf16 = 16 B. Slice per v = 10240 B.
//   f = 2g + nf;  g: 0=W000 1=W110 2=W011 3=W101 4=W111;  w = nf*16 + (l&15)
//   element j: scale_g * Wg[(8*(l>>4)+j)*1024 + v*32 + w].  Total 327680 B.
// ---------------------------------------------------------------------------
__global__ __launch_bounds__(256) void prep_weights(
    const float* __restrict__ W000, const float* __restrict__ W110,
    const float* __restrict__ W011, const float* __restrict__ W101,
    const float* __restrict__ W111, short* __restrict__ wsB)
{
    const int t = blockIdx.x * 256 + threadIdx.x;   // 0 .. 5*32768-1
    if (t >= 5 * 32768) return;
    const int g   = t >> 15;
    const int idx = t & 32767;          // u*1024 + v*32 + w
    const int u = idx >> 10, v = (idx >> 5) & 31, w = idx & 31;
    const float* Wp = (g == 0) ? W000 : (g == 1) ? W110 : (g == 2) ? W011
                    : (g == 3) ? W101 : W111;
    const float s = (g == 0) ? C_OUT0
                  : (g == 1) ? C_OUT0 * INV_SQRT3
                  : (g == 4) ? C_OUT1 * INV_SQRT6
                  :            C_OUT1 * INV_SQRT3;
    const int f = 2 * g + (w >> 4);
    const int l = ((u >> 3) << 4) | (w & 15);
    const int j = u & 7;
    wsB[(((v * 10 + f) * 64) + l) * 8 + j] = bfbits(s * Wp[idx]);
}

// ---------------------------------------------------------------------------
// main: 256 threads = 4 waves = 1 edge-tile (16 edges) x 4 v-quarters (vq).
// LDS 18688 B: rawS [16][33 float4] (8448; x1 stage -> x2 stage -> reduce
// scratch) + bT [128 slices][20 floats] (10240): bT[(v*4+c)*20 + e] = b_c[e,v].
// __launch_bounds__(256, 8): 8 waves/EU -> VGPR cap 64 -> 8 blocks/CU.
// ---------------------------------------------------------------------------
__global__ __launch_bounds__(256, 8) void e3nn_o8(
    const float* __restrict__ x1, const float* __restrict__ x2,
    const short8* __restrict__ wsB, float* __restrict__ out, int E)
{
    __shared__ __align__(16) float rawS[16 * 132];   // 8448 B
    __shared__ __align__(16) float bT[128 * 20];     // 10240 B
    float4* raw4 = (float4*)rawS;

    const int tid   = threadIdx.x;
    const int l     = tid & 63;
    const int vq    = tid >> 6;          // v-quarter: v in [8*vq, 8*vq+8)
    const int eBase = blockIdx.x * 16;

    // ---- phase 1: stage x1 tile (16 edges x 32 float4), padded stride 33 ----
    const float4* x1v = (const float4*)x1;
    for (int i = tid; i < 16 * 32; i += 256) {
        const int e = i >> 5, c4 = i & 31;
        float4 val = {0.f, 0.f, 0.f, 0.f};
        if (eBase + e < E) val = x1v[(size_t)(eBase + e) * 32 + c4];
        raw4[e * 33 + c4] = val;
    }
    __syncthreads();

    // ---- static bf16 A-fragments (identical in all 4 waves; broadcast reads) ----
    const int eloc = l & 15;
    const int u0   = (l >> 4) * 8;
    short8 Aa0, Aax, Aay, Aaz;
    {
        const float* row = rawS + eloc * 132;
        #pragma unroll
        for (int j = 0; j < 8; ++j) {
            Aa0[j] = bfbits(row[u0 + j]);
            Aax[j] = bfbits(row[32 + 3 * (u0 + j) + 0]);
            Aay[j] = bfbits(row[32 + 3 * (u0 + j) + 1]);
            Aaz[j] = bfbits(row[32 + 3 * (u0 + j) + 2]);
        }
    }
    __syncthreads();   // x1 stage dead

    // ---- phase 2a: stage x2 raw (same coalesced pattern) ----
    const float4* x2v = (const float4*)x2;
    for (int i = tid; i < 16 * 32; i += 256) {
        const int e = i >> 5, c4 = i & 31;
        float4 val = {0.f, 0.f, 0.f, 0.f};
        if (eBase + e < E) val = x2v[(size_t)(eBase + e) * 32 + c4];
        raw4[e * 33 + c4] = val;
    }
    __syncthreads();

    // ---- phase 2b: transpose to bT[(v*4+c)*20 + e] ----
    {
        const int s  = tid >> 1;        // slice = v*4 + c, 0..127
        const int eh = tid & 1;
        const int v  = s >> 2, c = s & 3;
        const int r  = (c == 0) ? v : (32 + v * 3 + (c - 1));
        #pragma unroll
        for (int k = 0; k < 8; ++k) {
            const int e = eh * 8 + k;
            bT[s * 20 + e] = rawS[e * 132 + r];
        }
    }
    __syncthreads();

    // ---- main v loop: 8 iters; 22 static-A MFMAs + 32 f32x4 stage-2 FMAs ----
    const f32x4 zero = {0.f, 0.f, 0.f, 0.f};
    f32x4 acc0[2]    = {zero, zero};
    f32x4 acc1[3][2] = {{zero, zero}, {zero, zero}, {zero, zero}};

    const short8* wb  = wsB + l;
    const float*  bTt = bT + (l >> 4) * 4;   // + (v*4+c)*20; 16B-aligned (80B*s)

    #pragma unroll 2
    for (int v = vq * 8; v < vq * 8 + 8; ++v) {
        const short8* p = wb + v * 640;   // (v*10 + f)*64 + l
        short8 Bf[10];
        #pragma unroll
        for (int f = 0; f < 10; ++f) Bf[f] = p[f * 64];

        // b-vectors for this lane's 4 D-rows (broadcast within 16-lane group)
        const f32x4 B0 = *(const f32x4*)(bTt + (v * 4 + 0) * 20);
        const f32x4 Bx = *(const f32x4*)(bTt + (v * 4 + 1) * 20);
        const f32x4 By = *(const f32x4*)(bTt + (v * 4 + 2) * 20);
        const f32x4 Bz = *(const f32x4*)(bTt + (v * 4 + 3) * 20);

        #pragma unroll
        for (int nf = 0; nf < 2; ++nf) {
            const f32x4 G000  = __builtin_amdgcn_mfma_f32_16x16x32_bf16(Aa0, Bf[0 + nf], zero, 0, 0, 0);
            const f32x4 G110x = __builtin_amdgcn_mfma_f32_16x16x32_bf16(Aax, Bf[2 + nf], zero, 0, 0, 0);
            const f32x4 G110y = __builtin_amdgcn_mfma_f32_16x16x32_bf16(Aay, Bf[2 + nf], zero, 0, 0, 0);
            const f32x4 G110z = __builtin_amdgcn_mfma_f32_16x16x32_bf16(Aaz, Bf[2 + nf], zero, 0, 0, 0);
            acc0[nf] += B0 * G000 + Bx * G110x + By * G110y + Bz * G110z;

            const f32x4 G011  = __builtin_amdgcn_mfma_f32_16x16x32_bf16(Aa0, Bf[4 + nf], zero, 0, 0, 0);
            acc1[0][nf] += Bx * G011;
            acc1[1][nf] += By * G011;
            acc1[2][nf] += Bz * G011;

            const f32x4 G101x = __builtin_amdgcn_mfma_f32_16x16x32_bf16(Aax, Bf[6 + nf], zero, 0, 0, 0);
            const f32x4 G101y = __builtin_amdgcn_mfma_f32_16x16x32_bf16(Aay, Bf[6 + nf], zero, 0, 0, 0);
            const f32x4 G101z = __builtin_amdgcn_mfma_f32_16x16x32_bf16(Aaz, Bf[6 + nf], zero, 0, 0, 0);
            acc1[0][nf] += B0 * G101x;
            acc1[1][nf] += B0 * G101y;
            acc1[2][nf] += B0 * G101z;

            const f32x4 G111x = __builtin_amdgcn_mfma_f32_16x16x32_bf16(Aax, Bf[8 + nf], zero, 0, 0, 0);
            const f32x4 G111y = __builtin_amdgcn_mfma_f32_16x16x32_bf16(Aay, Bf[8 + nf], zero, 0, 0, 0);
            const f32x4 G111z = __builtin_amdgcn_mfma_f32_16x16x32_bf16(Aaz, Bf[8 + nf], zero, 0, 0, 0);
            acc1[0][nf] += Bz * G111y - By * G111z;
            acc1[1][nf] += Bx * G111z - Bz * G111x;
            acc1[2][nf] += By * G111x - Bx * G111y;
        }
    }

    // ---- sequential 4-way reduce through rawS (64 rows x 33, conflict-free) ----
    float* red = rawS;
    const int rbase = l * 33;   // 64 rows x 33 floats = 8448 B, fits rawS

    __syncthreads();   // all waves done with bT/rawS phases
    if (vq == 3) {
        #pragma unroll
        for (int nf = 0; nf < 2; ++nf)
            #pragma unroll
            for (int r = 0; r < 4; ++r) {
                red[rbase + (0 + nf) * 4 + r] = acc0[nf][r];
                red[rbase + (2 + nf) * 4 + r] = acc1[0][nf][r];
                red[rbase + (4 + nf) * 4 + r] = acc1[1][nf][r];
                red[rbase + (6 + nf) * 4 + r] = acc1[2][nf][r];
            }
    }
    __syncthreads();
    if (vq == 2) {
        #pragma unroll
        for (int nf = 0; nf < 2; ++nf)
            #pragma unroll
            for (int r = 0; r < 4; ++r) {
                red[rbase + (0 + nf) * 4 + r] += acc0[nf][r];
                red[rbase + (2 + nf) * 4 + r] += acc1[0][nf][r];
                red[rbase + (4 + nf) * 4 + r] += acc1[1][nf][r];
                red[rbase + (6 + nf) * 4 + r] += acc1[2][nf][r];
            }
    }
    __syncthreads();
    if (vq == 1) {
        #pragma unroll
        for (int nf = 0; nf < 2; ++nf)
            #pragma unroll
            for (int r = 0; r < 4; ++r) {
                red[rbase + (0 + nf) * 4 + r] += acc0[nf][r];
                red[rbase + (2 + nf) * 4 + r] += acc1[0][nf][r];
                red[rbase + (4 + nf) * 4 + r] += acc1[1][nf][r];
                red[rbase + (6 + nf) * 4 + r] += acc1[2][nf][r];
            }
    }
    __syncthreads();

    // ---- epilogue from vq=0 wave (scales pre-baked into weights) ----
    if (vq == 0) {
        const int be0 = (l >> 4) * 4;
        #pragma unroll
        for (int nf = 0; nf < 2; ++nf) {
            const int w = nf * 16 + (l & 15);
            #pragma unroll
            for (int r = 0; r < 4; ++r) {
                const int ge = eBase + be0 + r;
                if (ge < E) {
                    const size_t base = (size_t)ge * 128;
                    out[base + w] =
                        acc0[nf][r] + red[rbase + (0 + nf) * 4 + r];
                    out[base + 32 + 3 * w + 0] =
                        acc1[0][nf][r] + red[rbase + (2 + nf) * 4 + r];
                    out[base + 32 + 3 * w + 1] =
                        acc1[1][nf][r] + red[rbase + (4 + nf) * 4 + r];
                    out[base + 32 + 3 * w + 2] =
                        acc1[2][nf][r] + red[rbase + (6 + nf) * 4 + r];
                }
            }
        }
    }
}

extern "C" void kernel_launch(void* const* d_in, const int* in_sizes, int n_in,
                              void* d_out, int out_size, void* d_ws, size_t ws_size,
                              hipStream_t stream) {
    const float* x1   = (const float*)d_in[0];
    const float* x2   = (const float*)d_in[1];
    const float* W000 = (const float*)d_in[2];
    const float* W110 = (const float*)d_in[3];
    const float* W011 = (const float*)d_in[4];
    const float* W101 = (const float*)d_in[5];
    const float* W111 = (const float*)d_in[6];
    float* out = (float*)d_out;

    const int E = in_sizes[0] / 128;

    hipLaunchKernelGGL(prep_weights, dim3((5 * 32768 + 255) / 256), dim3(256), 0, stream,
                       W000, W110, W011, W101, W111, (short*)d_ws);

    const int grid = (E + 15) / 16;
    hipLaunchKernelGGL(e3nn_o8, dim3(grid), dim3(256), 0, stream,
                       x1, x2, (const short8*)d_ws, out, E);
}

// Round 17
// 78.773 us; speedup vs baseline: 6.8655x; 6.8655x over previous
//
#include <hip/hip_runtime.h>
#include <hip/hip_bf16.h>

// E3nnSimpleEdgeBlock, two-stage factorized MFMA — FINAL (green R15, 79.5us).
// Persistent blocks (1792 = 7/CU) grid-stride over 3125 16-edge tiles;
// per tile: 4 waves = 4 v-quarters, sequential LDS reduce.
//
// Stage 1 (MFMA, static A): G_p,c[e,w] = sum_u a_c[e,u] * (scale*Wp)[u,v,w]
// Stage 2 (f32 VALU on D-frags): acc[e,w] += b_c[e,v] * G_p,c[e,w]
//
// Structural floor arithmetic (session R1-R16): MFMA pipe needs ~17.5us at
// 100% util (measured 18% @ 80us = near-minimum instr count); VALU pipe ~38us
// busy; occupancy pinned at 4 waves/SIMD by the VGPR 65-128 shelf (76 needed;
// forcing 64 spills catastrophically — R16). All ILP/TLP/scheduling levers
// measured at <5%: this is the plateau.
//
// mfma_f32_16x16x32_bf16 lane mapping (m89-verified):
//   A[row=l&15][k=8*(l>>4)+j]  B[k=8*(l>>4)+j][col=l&15]  D[row=4*(l>>4)+r][col=l&15]

typedef __attribute__((ext_vector_type(8))) short short8;   // 8 bf16 (4 VGPRs)
typedef __attribute__((ext_vector_type(4))) float f32x4;

static constexpr float C_OUT0    = 0.022097086912079608f; // 1/sqrt(2048)
static constexpr float C_OUT1    = 0.03125f;              // 1/sqrt(1024)
static constexpr float INV_SQRT3 = 0.57735026918962576f;
static constexpr float INV_SQRT6 = 0.40824829046386302f;

static __device__ __forceinline__ short bfbits(float x) {
    __hip_bfloat16 h = __float2bfloat16(x);
    return __builtin_bit_cast(short, h);
}

// ---------------------------------------------------------------------------
// prep (post-timing-proven x9): bf16 B-fragment stream in d_ws.
// Layout: for v, frag f (0..9), lane l: 8 bf16 = 16 B. Slice per v = 10240 B.
//   f = 2g + nf;  g: 0=W000 1=W110 2=W011 3=W101 4=W111;  w = nf*16 + (l&15)
//   element j: scale_g * Wg[(8*(l>>4)+j)*1024 + v*32 + w].  Total 327680 B.
// ---------------------------------------------------------------------------
__global__ __launch_bounds__(256) void prep_weights(
    const float* __restrict__ W000, const float* __restrict__ W110,
    const float* __restrict__ W011, const float* __restrict__ W101,
    const float* __restrict__ W111, short* __restrict__ wsB)
{
    const int t = blockIdx.x * 256 + threadIdx.x;   // 0 .. 5*32768-1
    if (t >= 5 * 32768) return;
    const int g   = t >> 15;
    const int idx = t & 32767;          // u*1024 + v*32 + w
    const int u = idx >> 10, v = (idx >> 5) & 31, w = idx & 31;
    const float* Wp = (g == 0) ? W000 : (g == 1) ? W110 : (g == 2) ? W011
                    : (g == 3) ? W101 : W111;
    const float s = (g == 0) ? C_OUT0
                  : (g == 1) ? C_OUT0 * INV_SQRT3
                  : (g == 4) ? C_OUT1 * INV_SQRT6
                  :            C_OUT1 * INV_SQRT3;
    const int f = 2 * g + (w >> 4);
    const int l = ((u >> 3) << 4) | (w & 15);
    const int j = u & 7;
    wsB[(((v * 10 + f) * 64) + l) * 8 + j] = bfbits(s * Wp[idx]);
}

// ---------------------------------------------------------------------------
// main: persistent blocks; 256 threads = 4 waves = 4 v-quarters per tile.
// LDS 18688 B: rawS [16][33 float4] (8448; x1 stage -> x2 stage -> reduce
// scratch) + bT [128 slices][20 floats] (10240): bT[(v*4+c)*20 + e] = b_c[e,v].
// ---------------------------------------------------------------------------
#define NTILES(E)  (((E) + 15) / 16)
#define PGRID 1792   // 7 blocks/CU x 256 CUs (VGPR-cap residency)

__global__ __launch_bounds__(256) void e3nn_pers(
    const float* __restrict__ x1, const float* __restrict__ x2,
    const short8* __restrict__ wsB, float* __restrict__ out, int E)
{
    __shared__ __align__(16) float rawS[16 * 132];   // 8448 B
    __shared__ __align__(16) float bT[128 * 20];     // 10240 B
    float4* raw4 = (float4*)rawS;

    const int tid  = threadIdx.x;
    const int l    = tid & 63;
    const int vq   = tid >> 6;          // v-quarter: v in [8*vq, 8*vq+8)
    const int eloc = l & 15;
    const int u0   = (l >> 4) * 8;
    const int nt   = NTILES(E);

    const float4* x1v = (const float4*)x1;
    const float4* x2v = (const float4*)x2;
    const short8* wb  = wsB + l;
    const float*  bTt = bT + (l >> 4) * 4;
    const f32x4 zero = {0.f, 0.f, 0.f, 0.f};

    for (int tile = blockIdx.x; tile < nt; tile += PGRID) {
        const int eBase = tile * 16;

        __syncthreads();   // previous tile's epilogue reads done before restage

        // ---- phase 1: stage x1 tile (16 edges x 32 float4), stride 33 ----
        for (int i = tid; i < 16 * 32; i += 256) {
            const int e = i >> 5, c4 = i & 31;
            float4 val = {0.f, 0.f, 0.f, 0.f};
            if (eBase + e < E) val = x1v[(size_t)(eBase + e) * 32 + c4];
            raw4[e * 33 + c4] = val;
        }
        __syncthreads();

        // ---- static bf16 A-fragments (identical in all 4 waves) ----
        short8 Aa0, Aax, Aay, Aaz;
        {
            const float* row = rawS + eloc * 132;
            #pragma unroll
            for (int j = 0; j < 8; ++j) {
                Aa0[j] = bfbits(row[u0 + j]);
                Aax[j] = bfbits(row[32 + 3 * (u0 + j) + 0]);
                Aay[j] = bfbits(row[32 + 3 * (u0 + j) + 1]);
                Aaz[j] = bfbits(row[32 + 3 * (u0 + j) + 2]);
            }
        }
        __syncthreads();   // x1 stage dead

        // ---- phase 2a: stage x2 raw ----
        for (int i = tid; i < 16 * 32; i += 256) {
            const int e = i >> 5, c4 = i & 31;
            float4 val = {0.f, 0.f, 0.f, 0.f};
            if (eBase + e < E) val = x2v[(size_t)(eBase + e) * 32 + c4];
            raw4[e * 33 + c4] = val;
        }
        __syncthreads();

        // ---- phase 2b: transpose to bT[(v*4+c)*20 + e] ----
        {
            const int s  = tid >> 1;        // slice = v*4 + c, 0..127
            const int eh = tid & 1;
            const int v  = s >> 2, c = s & 3;
            const int r  = (c == 0) ? v : (32 + v * 3 + (c - 1));
            #pragma unroll
            for (int k = 0; k < 8; ++k) {
                const int e = eh * 8 + k;
                bT[s * 20 + e] = rawS[e * 132 + r];
            }
        }
        __syncthreads();

        // ---- main v loop: 8 iters; 22 static-A MFMAs + stage-2 FMAs ----
        f32x4 acc0[2]    = {zero, zero};
        f32x4 acc1[3][2] = {{zero, zero}, {zero, zero}, {zero, zero}};

        #pragma unroll 2
        for (int v = vq * 8; v < vq * 8 + 8; ++v) {
            const short8* p = wb + v * 640;   // (v*10 + f)*64 + l
            short8 Bf[10];
            #pragma unroll
            for (int f = 0; f < 10; ++f) Bf[f] = p[f * 64];

            const f32x4 B0 = *(const f32x4*)(bTt + (v * 4 + 0) * 20);
            const f32x4 Bx = *(const f32x4*)(bTt + (v * 4 + 1) * 20);
            const f32x4 By = *(const f32x4*)(bTt + (v * 4 + 2) * 20);
            const f32x4 Bz = *(const f32x4*)(bTt + (v * 4 + 3) * 20);

            #pragma unroll
            for (int nf = 0; nf < 2; ++nf) {
                const f32x4 G000  = __builtin_amdgcn_mfma_f32_16x16x32_bf16(Aa0, Bf[0 + nf], zero, 0, 0, 0);
                const f32x4 G110x = __builtin_amdgcn_mfma_f32_16x16x32_bf16(Aax, Bf[2 + nf], zero, 0, 0, 0);
                const f32x4 G110y = __builtin_amdgcn_mfma_f32_16x16x32_bf16(Aay, Bf[2 + nf], zero, 0, 0, 0);
                const f32x4 G110z = __builtin_amdgcn_mfma_f32_16x16x32_bf16(Aaz, Bf[2 + nf], zero, 0, 0, 0);
                acc0[nf] += B0 * G000 + Bx * G110x + By * G110y + Bz * G110z;

                const f32x4 G011  = __builtin_amdgcn_mfma_f32_16x16x32_bf16(Aa0, Bf[4 + nf], zero, 0, 0, 0);
                acc1[0][nf] += Bx * G011;
                acc1[1][nf] += By * G011;
                acc1[2][nf] += Bz * G011;

                const f32x4 G101x = __builtin_amdgcn_mfma_f32_16x16x32_bf16(Aax, Bf[6 + nf], zero, 0, 0, 0);
                const f32x4 G101y = __builtin_amdgcn_mfma_f32_16x16x32_bf16(Aay, Bf[6 + nf], zero, 0, 0, 0);
                const f32x4 G101z = __builtin_amdgcn_mfma_f32_16x16x32_bf16(Aaz, Bf[6 + nf], zero, 0, 0, 0);
                acc1[0][nf] += B0 * G101x;
                acc1[1][nf] += B0 * G101y;
                acc1[2][nf] += B0 * G101z;

                const f32x4 G111x = __builtin_amdgcn_mfma_f32_16x16x32_bf16(Aax, Bf[8 + nf], zero, 0, 0, 0);
                const f32x4 G111y = __builtin_amdgcn_mfma_f32_16x16x32_bf16(Aay, Bf[8 + nf], zero, 0, 0, 0);
                const f32x4 G111z = __builtin_amdgcn_mfma_f32_16x16x32_bf16(Aaz, Bf[8 + nf], zero, 0, 0, 0);
                acc1[0][nf] += Bz * G111y - By * G111z;
                acc1[1][nf] += Bx * G111z - Bz * G111x;
                acc1[2][nf] += By * G111x - Bx * G111y;
            }
        }

        // ---- sequential 4-way reduce through rawS (stride-33 rows) ----
        float* red = rawS;
        const int rbase = l * 33;

        __syncthreads();   // all waves done with bT/rawS phases
        if (vq == 3) {
            #pragma unroll
            for (int nf = 0; nf < 2; ++nf)
                #pragma unroll
                for (int r = 0; r < 4; ++r) {
                    red[rbase + (0 + nf) * 4 + r] = acc0[nf][r];
                    red[rbase + (2 + nf) * 4 + r] = acc1[0][nf][r];
                    red[rbase + (4 + nf) * 4 + r] = acc1[1][nf][r];
                    red[rbase + (6 + nf) * 4 + r] = acc1[2][nf][r];
                }
        }
        __syncthreads();
        if (vq == 2) {
            #pragma unroll
            for (int nf = 0; nf < 2; ++nf)
                #pragma unroll
                for (int r = 0; r < 4; ++r) {
                    red[rbase + (0 + nf) * 4 + r] += acc0[nf][r];
                    red[rbase + (2 + nf) * 4 + r] += acc1[0][nf][r];
                    red[rbase + (4 + nf) * 4 + r] += acc1[1][nf][r];
                    red[rbase + (6 + nf) * 4 + r] += acc1[2][nf][r];
                }
        }
        __syncthreads();
        if (vq == 1) {
            #pragma unroll
            for (int nf = 0; nf < 2; ++nf)
                #pragma unroll
                for (int r = 0; r < 4; ++r) {
                    red[rbase + (0 + nf) * 4 + r] += acc0[nf][r];
                    red[rbase + (2 + nf) * 4 + r] += acc1[0][nf][r];
                    red[rbase + (4 + nf) * 4 + r] += acc1[1][nf][r];
                    red[rbase + (6 + nf) * 4 + r] += acc1[2][nf][r];
                }
        }
        __syncthreads();

        // ---- epilogue from vq=0 wave (scales pre-baked into weights) ----
        if (vq == 0) {
            const int be0 = (l >> 4) * 4;
            #pragma unroll
            for (int nf = 0; nf < 2; ++nf) {
                const int w = nf * 16 + (l & 15);
                #pragma unroll
                for (int r = 0; r < 4; ++r) {
                    const int ge = eBase + be0 + r;
                    if (ge < E) {
                        const size_t base = (size_t)ge * 128;
                        out[base + w] =
                            acc0[nf][r] + red[rbase + (0 + nf) * 4 + r];
                        out[base + 32 + 3 * w + 0] =
                            acc1[0][nf][r] + red[rbase + (2 + nf) * 4 + r];
                        out[base + 32 + 3 * w + 1] =
                            acc1[1][nf][r] + red[rbase + (4 + nf) * 4 + r];
                        out[base + 32 + 3 * w + 2] =
                            acc1[2][nf][r] + red[rbase + (6 + nf) * 4 + r];
                    }
                }
            }
        }
    }
}

extern "C" void kernel_launch(void* const* d_in, const int* in_sizes, int n_in,
                              void* d_out, int out_size, void* d_ws, size_t ws_size,
                              hipStream_t stream) {
    const float* x1   = (const float*)d_in[0];
    const float* x2   = (const float*)d_in[1];
    const float* W000 = (const float*)d_in[2];
    const float* W110 = (const float*)d_in[3];
    const float* W011 = (const float*)d_in[4];
    const float* W101 = (const float*)d_in[5];
    const float* W111 = (const float*)d_in[6];
    float* out = (float*)d_out;

    const int E = in_sizes[0] / 128;

    hipLaunchKernelGGL(prep_weights, dim3((5 * 32768 + 255) / 256), dim3(256), 0, stream,
                       W000, W110, W011, W101, W111, (short*)d_ws);

    const int grid = (NTILES(E) < PGRID) ? NTILES(E) : PGRID;
    hipLaunchKernelGGL(e3nn_pers, dim3(grid), dim3(256), 0, stream,
                       x1, x2, (const short8*)d_ws, out, E);
}